// Round 1
// baseline (48.763 us; speedup 1.0000x reference)
//
#include <hip/hip_runtime.h>

// Per-edge dot product: score[e] = sum_d h[src[e],d] * h[dst[e],d]
// h: [N_NODES, 32] f32, src/dst: [E] int32, out: [E] f32.
//
// 8 lanes cooperate on one edge: lane g loads float4 #g of each 32-float row
// (128 B row fully coalesced across the group), partial dot, then 3-step
// shfl_xor reduction within the 8-lane group.

constexpr int D_FEAT = 32;

__global__ void __launch_bounds__(256) edge_dot_kernel(
    const float* __restrict__ h,
    const int* __restrict__ src,
    const int* __restrict__ dst,
    float* __restrict__ out,
    int n_edges)
{
    const int g = threadIdx.x & 7;  // lane-in-group (covers float4 #g of the row)
    const int group = (blockIdx.x * blockDim.x + threadIdx.x) >> 3;
    const int n_groups = (gridDim.x * blockDim.x) >> 3;

    for (int e = group; e < n_edges; e += n_groups) {
        const int s = src[e];
        const int d = dst[e];
        const float4 a = reinterpret_cast<const float4*>(h + (size_t)s * D_FEAT)[g];
        const float4 b = reinterpret_cast<const float4*>(h + (size_t)d * D_FEAT)[g];
        float acc = a.x * b.x + a.y * b.y + a.z * b.z + a.w * b.w;
        // reduce across the 8-lane group (xor masks < 8 stay within the group)
        acc += __shfl_xor(acc, 1);
        acc += __shfl_xor(acc, 2);
        acc += __shfl_xor(acc, 4);
        if (g == 0) out[e] = acc;
    }
}

extern "C" void kernel_launch(void* const* d_in, const int* in_sizes, int n_in,
                              void* d_out, int out_size, void* d_ws, size_t ws_size,
                              hipStream_t stream) {
    const float* h   = (const float*)d_in[0];
    const int*   src = (const int*)d_in[1];
    const int*   dst = (const int*)d_in[2];
    float*       out = (float*)d_out;
    const int n_edges = in_sizes[1];

    const int block = 256;
    const int grid = 2048;  // grid-stride; 65536 edge-groups
    edge_dot_kernel<<<grid, block, 0, stream>>>(h, src, dst, out, n_edges);
}

// Round 2
// 41.532 us; speedup vs baseline: 1.1741x; 1.1741x over previous
//
#include <hip/hip_runtime.h>

// score[e] = dot(h[src[e]], h[dst[e]]), D=32.
// Strategy: h (12.8 MB f32) doesn't fit per-XCD 4 MB L2 -> 147 MB of L2-fill
// traffic on random gathers. Convert h to bf16 (6.4 MB) in d_ws once per call,
// then gather 64-B rows: 4 lanes/edge x 16 B (8 bf16), f32 accumulate.

constexpr int D_FEAT = 32;

static __device__ __forceinline__ float bf_lo(unsigned u) {
    return __uint_as_float(u << 16);
}
static __device__ __forceinline__ float bf_hi(unsigned u) {
    return __uint_as_float(u & 0xffff0000u);
}
static __device__ __forceinline__ unsigned short f2bf_rne(float f) {
    unsigned u = __float_as_uint(f);
    u = (u + 0x7fffu + ((u >> 16) & 1u)) >> 16;  // round-nearest-even
    return (unsigned short)u;
}

__global__ void __launch_bounds__(256) convert_h_bf16(
    const float4* __restrict__ h4, ushort4* __restrict__ hb4, int n4)
{
    int i = blockIdx.x * blockDim.x + threadIdx.x;
    const int stride = gridDim.x * blockDim.x;
    for (; i < n4; i += stride) {
        const float4 v = h4[i];
        ushort4 o;
        o.x = f2bf_rne(v.x);
        o.y = f2bf_rne(v.y);
        o.z = f2bf_rne(v.z);
        o.w = f2bf_rne(v.w);
        hb4[i] = o;
    }
}

__global__ void __launch_bounds__(256) edge_dot_bf16(
    const unsigned short* __restrict__ hb,
    const int* __restrict__ src,
    const int* __restrict__ dst,
    float* __restrict__ out,
    int n_edges)
{
    const int g = threadIdx.x & 3;  // lane-in-group: 4 lanes/edge, 16 B each
    const int group = (blockIdx.x * blockDim.x + threadIdx.x) >> 2;
    const int n_groups = (gridDim.x * blockDim.x) >> 2;

    for (int e = group; e < n_edges; e += n_groups) {
        const int s = src[e];
        const int d = dst[e];
        const uint4 a = reinterpret_cast<const uint4*>(hb + (size_t)s * D_FEAT)[g];
        const uint4 b = reinterpret_cast<const uint4*>(hb + (size_t)d * D_FEAT)[g];
        float acc;
        acc  = bf_lo(a.x) * bf_lo(b.x) + bf_hi(a.x) * bf_hi(b.x);
        acc += bf_lo(a.y) * bf_lo(b.y) + bf_hi(a.y) * bf_hi(b.y);
        acc += bf_lo(a.z) * bf_lo(b.z) + bf_hi(a.z) * bf_hi(b.z);
        acc += bf_lo(a.w) * bf_lo(b.w) + bf_hi(a.w) * bf_hi(b.w);
        acc += __shfl_xor(acc, 1);
        acc += __shfl_xor(acc, 2);
        if (g == 0) out[e] = acc;
    }
}

// f32 fallback (if ws too small for bf16 copy of h)
__global__ void __launch_bounds__(256) edge_dot_f32(
    const float* __restrict__ h,
    const int* __restrict__ src,
    const int* __restrict__ dst,
    float* __restrict__ out,
    int n_edges)
{
    const int g = threadIdx.x & 7;
    const int group = (blockIdx.x * blockDim.x + threadIdx.x) >> 3;
    const int n_groups = (gridDim.x * blockDim.x) >> 3;
    for (int e = group; e < n_edges; e += n_groups) {
        const int s = src[e];
        const int d = dst[e];
        const float4 a = reinterpret_cast<const float4*>(h + (size_t)s * D_FEAT)[g];
        const float4 b = reinterpret_cast<const float4*>(h + (size_t)d * D_FEAT)[g];
        float acc = a.x * b.x + a.y * b.y + a.z * b.z + a.w * b.w;
        acc += __shfl_xor(acc, 1);
        acc += __shfl_xor(acc, 2);
        acc += __shfl_xor(acc, 4);
        if (g == 0) out[e] = acc;
    }
}

extern "C" void kernel_launch(void* const* d_in, const int* in_sizes, int n_in,
                              void* d_out, int out_size, void* d_ws, size_t ws_size,
                              hipStream_t stream) {
    const float* h   = (const float*)d_in[0];
    const int*   src = (const int*)d_in[1];
    const int*   dst = (const int*)d_in[2];
    float*       out = (float*)d_out;
    const int n_h     = in_sizes[0];           // N_NODES * D_FEAT
    const int n_edges = in_sizes[1];

    const size_t need = (size_t)n_h * sizeof(unsigned short);
    if (ws_size >= need) {
        unsigned short* hb = (unsigned short*)d_ws;
        const int n4 = n_h / 4;
        convert_h_bf16<<<2048, 256, 0, stream>>>(
            (const float4*)h, (ushort4*)hb, n4);
        edge_dot_bf16<<<2048, 256, 0, stream>>>(hb, src, dst, out, n_edges);
    } else {
        edge_dot_f32<<<2048, 256, 0, stream>>>(h, src, dst, out, n_edges);
    }
}